// Round 8
// baseline (460.765 us; speedup 1.0000x reference)
//
#include <hip/hip_runtime.h>

typedef __bf16 bf16;
typedef __bf16 bf16x4 __attribute__((ext_vector_type(4)));
typedef __bf16 bf16x8 __attribute__((ext_vector_type(8)));
typedef float  f32x4  __attribute__((ext_vector_type(4)));

#define B_ 2048
#define T_ 128
#define C_ 256
#define H_ 64

// LDS layout (bytes):
//  proj phase:  cb0[128][68] @0 (17408), cb1[128][68] @17408  — x K-chunk double buffer
//               (chunk fetch of c+1 overlaps proj MFMAs of c; stride 68 -> dword
//                stride 34 -> ~2-way bank pattern, measured 0 conflicts in r6)
//  QKV phase:   Qs[128][68] @0, Ks[128][68] @17408, Vt[64][132] @34816 (16896)
//  P phase:     Ps[128][132] @0 (33792) — aliases Qs/Ks after S reads done
// high-water 51712; 3 blocks/CU (155136 <= 163840) -> 12 waves/CU, up from r7's 8.
// r7's wins preserved: nt-sliced proj (24 Wt L2 loads/wave, 8x reuse), x fetched
// exactly once, r-outer direct store epilogue.
#define LDXC 68
#define LDQ 68
#define LDV 132
#define SMEM_BYTES 51712

__global__ void wt_kernel(const float* __restrict__ Wk, const float* __restrict__ Wq,
                          const float* __restrict__ Wv, bf16* __restrict__ Wt) {
    int o = blockIdx.x * 256 + threadIdx.x;     // 0..49151
    int slot = o >> 14;
    int r    = o & 16383;                       // coalesced source read
    int cc   = r >> 6;
    int h    = r & 63;
    const float* src = (slot == 0) ? Wq : (slot == 1 ? Wk : Wv);
    Wt[slot * 16384 + h * 256 + cc] = (bf16)src[r];
}

__global__ void __launch_bounds__(256, 3)
attn_kernel(const float* __restrict__ xg, const bf16* __restrict__ Wt,
            float* __restrict__ outg) {
    __shared__ __align__(16) char smem_raw[SMEM_BYTES];
    bf16* cb0 = (bf16*)smem_raw;                 // [128][68] chunk buf 0
    bf16* cb1 = (bf16*)(smem_raw + 17408);       // [128][68] chunk buf 1
    bf16* Qs  = (bf16*)smem_raw;                 // [128][68]  (aliases cb0)
    bf16* Ks  = (bf16*)(smem_raw + 17408);       // [128][68]  (aliases cb1)
    bf16* Vt  = (bf16*)(smem_raw + 34816);       // [64][132]
    bf16* Ps  = (bf16*)smem_raw;                 // [128][132]

    const int tid  = threadIdx.x;
    const int b    = blockIdx.x;
    const int w    = tid >> 6;
    const int lane = tid & 63;
    const int quad = lane >> 4;
    const int n16  = lane & 15;

    const f32x4 zero4 = {0.f, 0.f, 0.f, 0.f};
    const float*  xbp = xg + (size_t)b * (T_ * C_);
    const ushort* WtU = (const ushort*)Wt;

    // staging coords: i in 0..7: f = i*256+tid; row t = f>>4; col4 = (f&15)*4
    // (16 threads cover one row's 64-float chunk: 256B contiguous segments)

    // ---------------- stage chunk 0 ----------------
    #pragma unroll
    for (int i = 0; i < 8; i++) {
        int f = i * 256 + tid;
        int t = f >> 4, cc = (f & 15) * 4;
        float4 v = *(const float4*)(xbp + t * C_ + cc);
        bf16x4 bv = {(bf16)v.x, (bf16)v.y, (bf16)v.z, (bf16)v.w};
        *(bf16x4*)(cb0 + t * LDXC + cc) = bv;
    }
    __syncthreads();                             // chunk 0 visible

    // ---------------- projections: nt-sliced, K-chunked double buffer ----------------
    // wave w owns nt tiles 3w..3w+2 across all 8 row-tiles: Wt fragment reuse 8x
    const int w3 = 3 * w;
    const ushort* wb0 = WtU + ((w3 + 0) >> 2) * 16384 + (16 * ((w3 + 0) & 3) + n16) * 256 + 8 * quad;
    const ushort* wb1 = WtU + ((w3 + 1) >> 2) * 16384 + (16 * ((w3 + 1) & 3) + n16) * 256 + 8 * quad;
    const ushort* wb2 = WtU + ((w3 + 2) >> 2) * 16384 + (16 * ((w3 + 2) & 3) + n16) * 256 + 8 * quad;

    f32x4 acc[8][3];
    #pragma unroll
    for (int mt = 0; mt < 8; mt++)
        #pragma unroll
        for (int j = 0; j < 3; j++) acc[mt][j] = zero4;

    #pragma unroll
    for (int c = 0; c < 4; c++) {
        bf16* rb = (c & 1) ? cb1 : cb0;          // c is unrolled -> compile-time select
        bf16* sb = (c & 1) ? cb0 : cb1;
        float4 pf[8];
        if (c < 3) {                             // issue next-chunk HBM loads early;
            #pragma unroll                       // they complete under this chunk's MFMAs
            for (int i = 0; i < 8; i++) {
                int f = i * 256 + tid;
                int t = f >> 4, cc = (f & 15) * 4;
                pf[i] = *(const float4*)(xbp + t * C_ + (c + 1) * 64 + cc);
            }
        }
        #pragma unroll
        for (int kk = 0; kk < 2; kk++) {
            int kg = c * 64 + kk * 32;
            bf16x8 b0 = *(const bf16x8*)(wb0 + kg);
            bf16x8 b1 = *(const bf16x8*)(wb1 + kg);
            bf16x8 b2 = *(const bf16x8*)(wb2 + kg);
            #pragma unroll
            for (int mt = 0; mt < 8; mt++) {
                bf16x8 a = *(const bf16x8*)(rb + (16 * mt + n16) * LDXC + kk * 32 + 8 * quad);
                acc[mt][0] = __builtin_amdgcn_mfma_f32_16x16x32_bf16(a, b0, acc[mt][0], 0, 0, 0);
                acc[mt][1] = __builtin_amdgcn_mfma_f32_16x16x32_bf16(a, b1, acc[mt][1], 0, 0, 0);
                acc[mt][2] = __builtin_amdgcn_mfma_f32_16x16x32_bf16(a, b2, acc[mt][2], 0, 0, 0);
            }
        }
        if (c < 3) {                             // convert + store next chunk
            #pragma unroll
            for (int i = 0; i < 8; i++) {
                int f = i * 256 + tid;
                int t = f >> 4, cc = (f & 15) * 4;
                bf16x4 bv = {(bf16)pf[i].x, (bf16)pf[i].y, (bf16)pf[i].z, (bf16)pf[i].w};
                *(bf16x4*)(sb + t * LDXC + cc) = bv;
            }
        }
        __syncthreads();                         // next chunk written; this chunk's reads done
    }

    // ---------------- QKV write: Q (pre-scaled 2^-4, exact), K, Vt[h][t] ----------------
    // branches wave-uniform (w); chunk buffers dead -> Qs/Ks alias them safely
    #pragma unroll
    for (int j = 0; j < 3; j++) {
        int ng = w3 + j;
        if (ng < 4) {                            // Q, scaled
            int h = 16 * ng + n16;
            #pragma unroll
            for (int mt = 0; mt < 8; mt++) {
                int tbase = 16 * mt + 4 * quad;
                #pragma unroll
                for (int r = 0; r < 4; r++)
                    Qs[(tbase + r) * LDQ + h] = (bf16)(acc[mt][j][r] * 0.0625f);
            }
        } else if (ng < 8) {                     // K
            int h = 16 * (ng - 4) + n16;
            #pragma unroll
            for (int mt = 0; mt < 8; mt++) {
                int tbase = 16 * mt + 4 * quad;
                #pragma unroll
                for (int r = 0; r < 4; r++)
                    Ks[(tbase + r) * LDQ + h] = (bf16)acc[mt][j][r];
            }
        } else {                                 // V transposed: Vt[h][t]
            int h = 16 * (ng - 8) + n16;
            #pragma unroll
            for (int mt = 0; mt < 8; mt++) {
                bf16x4 pv = {(bf16)acc[mt][j][0], (bf16)acc[mt][j][1],
                             (bf16)acc[mt][j][2], (bf16)acc[mt][j][3]};
                *(bf16x4*)(Vt + h * LDV + 16 * mt + 4 * quad) = pv;
            }
        }
    }
    __syncthreads();                             // Q/K/V visible to all waves

    // ---------------- S = Q K^T, causal softmax (r6/r7-verified, 0 conflicts) ----------------
    f32x4 sacc[2][8];
    int mts[2] = {w, 7 - w};
    #pragma unroll
    for (int half = 0; half < 2; half++) {
        int mt = mts[half];
        int sT = ((mt >> 1) + 1) * 2;
        bf16x8 qa[2];
        #pragma unroll
        for (int ks = 0; ks < 2; ks++)
            qa[ks] = *(const bf16x8*)(Qs + (16 * mt + n16) * LDQ + 32 * ks + 8 * quad);
        #pragma unroll
        for (int nt = 0; nt < 8; nt++) {
            sacc[half][nt] = zero4;
            if (nt < sT) {
                bf16x8 kb0 = *(const bf16x8*)(Ks + (16 * nt + n16) * LDQ + 8 * quad);
                bf16x8 kb1 = *(const bf16x8*)(Ks + (16 * nt + n16) * LDQ + 32 + 8 * quad);
                sacc[half][nt] = __builtin_amdgcn_mfma_f32_16x16x32_bf16(qa[0], kb0, sacc[half][nt], 0, 0, 0);
                sacc[half][nt] = __builtin_amdgcn_mfma_f32_16x16x32_bf16(qa[1], kb1, sacc[half][nt], 0, 0, 0);
            }
        }
        #pragma unroll
        for (int r = 0; r < 4; r++) {
            int t = 16 * mt + 4 * quad + r;
            float mx = -3.0e38f;
            #pragma unroll
            for (int nt = 0; nt < 8; nt++) {
                if (nt < sT) {
                    float v = sacc[half][nt][r];                 // already C^-0.5-scaled
                    v = (16 * nt + n16 <= t) ? v : -3.0e38f;     // causal
                    sacc[half][nt][r] = v;
                    mx = fmaxf(mx, v);
                }
            }
            mx = fmaxf(mx, __shfl_xor(mx, 1));
            mx = fmaxf(mx, __shfl_xor(mx, 2));
            mx = fmaxf(mx, __shfl_xor(mx, 4));
            mx = fmaxf(mx, __shfl_xor(mx, 8));
            float sum = 0.f;
            #pragma unroll
            for (int nt = 0; nt < 8; nt++) {
                if (nt < sT) {
                    float p = __builtin_amdgcn_exp2f((sacc[half][nt][r] - mx) * 1.4426950408889634f);
                    sacc[half][nt][r] = p;
                    sum += p;
                }
            }
            sum += __shfl_xor(sum, 1);
            sum += __shfl_xor(sum, 2);
            sum += __shfl_xor(sum, 4);
            sum += __shfl_xor(sum, 8);
            float rinv = 1.0f / sum;
            #pragma unroll
            for (int nt = 0; nt < 8; nt++)
                if (nt < sT) sacc[half][nt][r] *= rinv;
        }
    }
    __syncthreads();                             // all Q/K reads done; Ps may alias

    #pragma unroll
    for (int half = 0; half < 2; half++) {
        int mt = mts[half];
        int sT = ((mt >> 1) + 1) * 2;
        #pragma unroll
        for (int nt = 0; nt < 8; nt++) {
            if (nt < sT) {
                #pragma unroll
                for (int r = 0; r < 4; r++)
                    Ps[(16 * mt + 4 * quad + r) * LDV + 16 * nt + n16] = (bf16)sacc[half][nt][r];
            }
        }
    }
    __syncthreads();                             // Ps visible

    // ---------------- O = P V, direct global store (r-outer: clean WRITE_SIZE) ----------------
    #pragma unroll
    for (int half = 0; half < 2; half++) {
        int mt  = mts[half];
        int kst = (mt >> 1) + 1;
        f32x4 oacc[4];
        #pragma unroll
        for (int nt = 0; nt < 4; nt++) oacc[nt] = zero4;
        #pragma unroll
        for (int ks = 0; ks < 4; ks++) {
            if (ks < kst) {
                bf16x8 pa = *(const bf16x8*)(Ps + (16 * mt + n16) * LDV + 32 * ks + 8 * quad);
                #pragma unroll
                for (int nt = 0; nt < 4; nt++) {
                    bf16x8 vb = *(const bf16x8*)(Vt + (16 * nt + n16) * LDV + 32 * ks + 8 * quad);
                    oacc[nt] = __builtin_amdgcn_mfma_f32_16x16x32_bf16(pa, vb, oacc[nt], 0, 0, 0);
                }
            }
        }
        float* ob = outg + ((size_t)b * T_ + 16 * mt + 4 * quad) * H_;
        #pragma unroll
        for (int r = 0; r < 4; r++)
            #pragma unroll
            for (int nt = 0; nt < 4; nt++)
                ob[r * H_ + 16 * nt + n16] = oacc[nt][r];
    }
}

extern "C" void kernel_launch(void* const* d_in, const int* in_sizes, int n_in,
                              void* d_out, int out_size, void* d_ws, size_t ws_size,
                              hipStream_t stream) {
    const float* x  = (const float*)d_in[0];
    const float* Wk = (const float*)d_in[1];
    const float* Wq = (const float*)d_in[2];
    const float* Wv = (const float*)d_in[3];
    bf16* Wt = (bf16*)d_ws;                      // 98304 B scratch
    wt_kernel<<<192, 256, 0, stream>>>(Wk, Wq, Wv, Wt);
    attn_kernel<<<B_, 256, 0, stream>>>(x, Wt, (float*)d_out);
}